// Round 5
// baseline (277.721 us; speedup 1.0000x reference)
//
#include <hip/hip_runtime.h>

constexpr int ATOM = 34;
constexpr int HID = 256;
constexpr int LATENT = 128;
constexpr int CELLS = 512;
constexpr int NN = 128;
constexpr int NA = NN * ATOM;   // 4352
#define NEGF (-9e15f)

// ---- shared pool layout (floats) ----
// GAT phase:   xl[128][36]@0, hlT[34][132]@4608, att[32][128]@9096,
//              wgT[34][36]@13192, fs@14416, fd@14544, bgs@14672, avs@14712
// phaseB:      wt[256][44]@0, wf[256][44]@11264, wf2[34*128]@22528,
//              dlT[34][33]@26880, sl[1024]@28032, bts@29056, bfs@29312,
//              xq[32][44]@29440   (xq written by GAT epilogue, survives overlay)
constexpr int POOL = 30848;     // 123.4 KB

// grid 256 = 64 batches x 4 row-quarters, block 1024 (16 waves)
template <bool FUSE_B>
__global__ __launch_bounds__(1024) void k_gat(
    const float* __restrict__ xsrc, const int* __restrict__ A,
    const float* __restrict__ Wg, const float* __restrict__ bg,
    const float* __restrict__ av, float* __restrict__ X,
    // phaseB args (used when FUSE_B)
    const float* __restrict__ xs,
    const float* __restrict__ Wt, const float* __restrict__ bt,
    const float* __restrict__ Wf, const float* __restrict__ bf,
    const float* __restrict__ Wf2, const float* __restrict__ bf2,
    float* __restrict__ DM)
{
    __shared__ __align__(16) float pool[POOL];
    const int b = blockIdx.x >> 2, q4 = blockIdx.x & 3;
    const int t = threadIdx.x, lane = t & 63, wave = t >> 6;
    const int p0 = q4 * 32;

    float* xl  = pool;            // [128][36]
    float* hlT = pool + 4608;     // [34][132]
    float* att = pool + 9096;     // [32][128]
    float* wgT = pool + 13192;    // [34][36]
    float* fs  = pool + 14416;
    float* fd  = pool + 14544;
    float* bgs = pool + 14672;
    float* avs = pool + 14712;
    float* xq  = pool + 29440;    // [32][44] (fused only)

    // ---- stage ----
    for (int i = t; i < ATOM * ATOM; i += 1024) {
        int d = i / ATOM, e = i - d * ATOM;
        wgT[e * 36 + d] = Wg[i];
    }
    if (t < 68)  wgT[(t >> 1) * 36 + 34 + (t & 1)] = 0.f;     // zero pads
    if (t < ATOM)     bgs[t] = bg[t];
    if (t < 2 * ATOM) avs[t] = av[t];
    const float* xp = xsrc + b * NA;
    for (int i = t; i < NA; i += 1024) xl[(i / ATOM) * 36 + (i % ATOM)] = xp[i];
    if (t < 256) xl[(t >> 1) * 36 + 34 + (t & 1)] = 0.f;      // zero pads
    __syncthreads();

    // ---- h^T = relu(x @ Wg + bg)^T : thread (n = t>>3, sub = t&7) ----
    {
        const int n = t >> 3, sub = t & 7;
        float xr[36];
        {
            float4* xr4 = (float4*)xr;
            const float4* xlr = (const float4*)(xl + n * 36);
            #pragma unroll
            for (int k = 0; k < 9; ++k) xr4[k] = xlr[k];
        }
        auto hbody = [&](int e) {
            float acc = bgs[e];
            const float4* wp = (const float4*)(wgT + e * 36);
            #pragma unroll
            for (int k = 0; k < 9; ++k) {
                float4 w4 = wp[k];
                acc += xr[4*k] * w4.x + xr[4*k+1] * w4.y + xr[4*k+2] * w4.z + xr[4*k+3] * w4.w;
            }
            hlT[e * 132 + n] = fmaxf(acc, 0.f);
        };
        #pragma unroll
        for (int j = 0; j < 4; ++j) hbody(sub + 8 * j);
        if (sub < 2) hbody(sub + 32);
    }
    __syncthreads();

    // ---- fs/fd ----
    if (t < 2 * NN) {
        const int n = t & (NN - 1), w = t >> 7;
        const float* avp = avs + w * ATOM;
        float acc = 0.f;
        #pragma unroll
        for (int d = 0; d < ATOM; ++d) acc += hlT[d * 132 + n] * avp[d];
        if (w == 0) fs[n] = acc; else fd[n] = acc;
    }
    __syncthreads();

    // ---- masked softmax: 16 waves x 2 rows ----
    const int* Ab = A + b * NN * NN;
    #pragma unroll
    for (int i = 0; i < 2; ++i) {
        int lp = wave * 2 + i, gp = p0 + lp;
        float fsv = fs[gp];
        unsigned long long m0 = __ballot(Ab[gp * NN + lane] > 0);
        unsigned long long m1 = __ballot(Ab[gp * NN + 64 + lane] > 0);
        float s0 = fsv + fd[lane];
        s0 = (s0 > 0.f) ? s0 : 0.01f * s0;
        if (!((m0 >> lane) & 1ull)) s0 = NEGF;
        float s1 = fsv + fd[64 + lane];
        s1 = (s1 > 0.f) ? s1 : 0.01f * s1;
        if (!((m1 >> lane) & 1ull)) s1 = NEGF;
        float mx = fmaxf(s0, s1);
        #pragma unroll
        for (int o = 32; o >= 1; o >>= 1) mx = fmaxf(mx, __shfl_xor(mx, o, 64));
        float e0 = __expf(s0 - mx), e1 = __expf(s1 - mx);
        float sm = e0 + e1;
        #pragma unroll
        for (int o = 32; o >= 1; o >>= 1) sm += __shfl_xor(sm, o, 64);
        float inv = 1.f / sm;
        att[lp * NN + lane]      = e0 * inv;
        att[lp * NN + 64 + lane] = e1 * inv;
    }
    __syncthreads();

    // ---- x_out = x + att @ h : thread (p = t>>5, g = t&15, kh = (t>>4)&1) ----
    {
        const int p = t >> 5, g = t & 15, kh = (t >> 4) & 1;
        const float4* ap  = (const float4*)(att + p * NN + kh * 64);
        const float4* h1p = (const float4*)(hlT + g * 132 + kh * 64);
        const float4* h2p = (const float4*)(hlT + (g + 16) * 132 + kh * 64);
        float a1 = 0.f, a2 = 0.f, a3 = 0.f;
        #pragma unroll
        for (int k = 0; k < 16; ++k) {
            float4 a4 = ap[k], x1 = h1p[k], x2 = h2p[k];
            a1 += a4.x * x1.x + a4.y * x1.y + a4.z * x1.z + a4.w * x1.w;
            a2 += a4.x * x2.x + a4.y * x2.y + a4.z * x2.z + a4.w * x2.w;
        }
        if (g < 2) {
            const float4* h3p = (const float4*)(hlT + (g + 32) * 132 + kh * 64);
            #pragma unroll
            for (int k = 0; k < 16; ++k) {
                float4 a4 = ap[k], x3 = h3p[k];
                a3 += a4.x * x3.x + a4.y * x3.y + a4.z * x3.z + a4.w * x3.w;
            }
        }
        a1 += __shfl_xor(a1, 16, 64);
        a2 += __shfl_xor(a2, 16, 64);
        a3 += __shfl_xor(a3, 16, 64);
        const int gp = p0 + p;
        if (FUSE_B) {
            if (kh == 0) {
                xq[p * 44 + g] = xl[gp * 36 + g] + a1;
                if (g < 2) xq[p * 44 + g + 32] = xl[gp * 36 + g + 32] + a3;
            } else {
                xq[p * 44 + g + 16] = xl[gp * 36 + g + 16] + a2;
                if (g >= 6) xq[p * 44 + 28 + g] = 0.f;   // zero pads 34..43
            }
        } else {
            float* Xr = X + b * NA + gp * ATOM;
            if (kh == 0) {
                Xr[g] = xl[gp * 36 + g] + a1;
                if (g < 2) Xr[g + 32] = xl[gp * 36 + g + 32] + a3;
            } else {
                Xr[g + 16] = xl[gp * 36 + g + 16] + a2;
            }
        }
    }

    if (!FUSE_B) return;

    // =================== phaseB (fused) ===================
    __syncthreads();                       // xq complete; xl/hlT/att now dead
    float* wt   = pool;                    // [256][44]
    float* wf   = pool + 11264;            // [256][44]
    float* wf2s = pool + 22528;            // [34*128]
    float* dlT  = pool + 26880;            // [34][33]
    float* sl   = pool + 28032;            // [1024]
    float* bts  = pool + 29056;            // [256]
    float* bfs  = pool + 29312;            // [40]

    for (int i = t; i < ATOM * HID; i += 1024) {
        int d = i >> 8, h = i & 255;       // Wt is [d][h]
        wt[h * 44 + d] = Wt[i];
    }
    for (int i = t; i < HID * ATOM; i += 1024) {
        int h = i / ATOM, j = i - h * ATOM; // Wf is [h][j]
        wf[h * 44 + j] = Wf[i];
    }
    for (int i = t; i < 2560; i += 1024) { // zero pads d/j 34..43
        int h = i / 10, c = 34 + i - (i / 10) * 10;
        wt[h * 44 + c] = 0.f; wf[h * 44 + c] = 0.f;
    }
    for (int i = t; i < ATOM * LATENT; i += 1024) wf2s[i] = Wf2[i];
    if (t < HID)  bts[t] = bt[t];
    if (t < ATOM) bfs[t] = bf[t];
    __syncthreads();

    // g=relu(x@Wt+bt); dpart=g@Wf : thread (row = t>>5, sub = t&15, half = (t>>4)&1)
    {
        const int row = t >> 5, sub = t & 15, half = (t >> 4) & 1;
        const int dbase = half * 20;
        float xr[20];
        {
            const float4* xp4 = (const float4*)(xq + row * 44 + dbase);
            float4* xr4 = (float4*)xr;
            #pragma unroll
            for (int k = 0; k < 5; ++k) xr4[k] = xp4[k];
        }
        float dp[20];
        #pragma unroll
        for (int j = 0; j < 20; ++j) dp[j] = 0.f;
        #pragma unroll
        for (int i = 0; i < 16; ++i) {
            const int h = sub + 16 * i;
            float part = 0.f;
            const float4* wtp = (const float4*)(wt + h * 44 + dbase);
            #pragma unroll
            for (int k = 0; k < 5; ++k) {
                float4 w4 = wtp[k];
                part += xr[4*k] * w4.x + xr[4*k+1] * w4.y + xr[4*k+2] * w4.z + xr[4*k+3] * w4.w;
            }
            float acc = fmaxf(part + __shfl_xor(part, 16, 64) + bts[h], 0.f);
            const float4* wfp = (const float4*)(wf + h * 44 + dbase);
            #pragma unroll
            for (int k = 0; k < 5; ++k) {
                float4 w4 = wfp[k];
                dp[4*k]   += acc * w4.x; dp[4*k+1] += acc * w4.y;
                dp[4*k+2] += acc * w4.z; dp[4*k+3] += acc * w4.w;
            }
        }
        __syncthreads();                   // all reads of wt/wf weights done
        {
            const int s8 = sub & 7;
            float* pl = (sub < 8) ? wt : wf;
            const int jbase = half * 20;
            #pragma unroll
            for (int jj = 0; jj < 20; ++jj) {
                int j = jbase + jj;
                if (j < ATOM) pl[(s8 * 32 + row) * ATOM + j] = dp[jj];
            }
        }
    }
    __syncthreads();

    // d = sum(partials) + bf + xs ; store transposed
    const float* xsq = xs + b * NA + p0 * ATOM;
    for (int i = t; i < 32 * ATOM; i += 1024) {
        int rr = i / ATOM, j = i - rr * ATOM;
        float dv = bfs[j] + xsq[rr * ATOM + j];
        #pragma unroll
        for (int s = 0; s < 8; ++s)
            dv += wt[(s * 32 + rr) * ATOM + j] + wf[(s * 32 + rr) * ATOM + j];
        dlT[j * 33 + rr] = dv;
    }
    __syncthreads();

    // d @ Wf2 + bf2, partial col-max (8 chunks x 4 rows)
    {
        const int l = t & 127, chunk = t >> 7;
        float w2r[ATOM];
        #pragma unroll
        for (int j = 0; j < ATOM; ++j) w2r[j] = wf2s[j * LATENT + l];
        const float bb = bf2[l];
        float mx = -3.4e38f;
        #pragma unroll
        for (int rr = 0; rr < 4; ++rr) {
            float acc = bb;
            #pragma unroll
            for (int j = 0; j < ATOM; ++j) acc += dlT[j * 33 + chunk * 4 + rr] * w2r[j];
            mx = fmaxf(mx, acc);
        }
        sl[chunk * 128 + l] = mx;
    }
    __syncthreads();
    if (t < LATENT) {
        float m = sl[t];
        #pragma unroll
        for (int s = 1; s < 8; ++s) m = fmaxf(m, sl[s * 128 + t]);
        DM[(b * 4 + q4) * LATENT + t] = m;
    }
}

// ---------------- k_dec: vec assembly + full decoder MLP ----------------
// grid 64, block 1024 (16 waves)
__global__ __launch_bounds__(1024) void k_dec(
    const float* __restrict__ DM, const float* __restrict__ cell,
    const float* __restrict__ W1, const float* __restrict__ b1,
    const float* __restrict__ W2, const float* __restrict__ b2,
    const float* __restrict__ W3, const float* __restrict__ b3,
    const float* __restrict__ W4, const float* __restrict__ b4,
    float* __restrict__ out)
{
    const int b = blockIdx.x, t = threadIdx.x, lane = t & 63, wave = t >> 6;
    __shared__ float vec[LATENT + CELLS];
    __shared__ float h1[128], h2[256], h3[512];
    __shared__ float sl[1024];
    if (t < LATENT) {
        float m = fmaxf(fmaxf(DM[(b*4+0)*LATENT + t], DM[(b*4+1)*LATENT + t]),
                        fmaxf(DM[(b*4+2)*LATENT + t], DM[(b*4+3)*LATENT + t]));
        vec[t] = 1.f / (1.f + __expf(-m));
    } else if (t >= 512) {
        int c = t - 512;
        vec[LATENT + c] = 1.f / (1.f + __expf(-cell[b * CELLS + c]));
    }
    __syncthreads();
    // L1: 640->128, 8-way k-split (80 each)
    {
        const int j = t & 127, part = t >> 7;
        float acc = 0.f;
        #pragma unroll 4
        for (int k = part * 80; k < part * 80 + 80; ++k)
            acc += vec[k] * W1[k * 128 + j];
        sl[part * 128 + j] = acc;
    }
    __syncthreads();
    if (t < 128) {
        float v = b1[t];
        #pragma unroll
        for (int p = 0; p < 8; ++p) v += sl[p * 128 + t];
        h1[t] = fmaxf(v, 0.f);
    }
    __syncthreads();
    // L2: 128->256, 4-way k-split (32 each)
    {
        const int j = t & 255, part = t >> 8;
        float acc = 0.f;
        #pragma unroll 4
        for (int k = part * 32; k < part * 32 + 32; ++k)
            acc += h1[k] * W2[k * 256 + j];
        sl[part * 256 + j] = acc;
    }
    __syncthreads();
    if (t < 256) h2[t] = fmaxf(sl[t] + sl[256 + t] + sl[512 + t] + sl[768 + t] + b2[t], 0.f);
    __syncthreads();
    // L3: 256->512, 2-way k-split (128 each)
    {
        const int j = t & 511, part = t >> 9;
        float acc = 0.f;
        #pragma unroll 4
        for (int k = part * 128; k < part * 128 + 128; ++k)
            acc += h2[k] * W3[k * 512 + j];
        sl[part * 512 + j] = acc;
    }
    __syncthreads();
    if (t < 512) h3[t] = fmaxf(sl[t] + sl[512 + t] + b3[t], 0.f);
    __syncthreads();
    float v = (t < 512) ? h3[t] * W4[t] : 0.f;
    #pragma unroll
    for (int o = 32; o >= 1; o >>= 1) v += __shfl_xor(v, o, 64);
    if (lane == 0) sl[wave] = v;
    __syncthreads();
    if (t == 0) {
        float s = b4[0];
        #pragma unroll
        for (int w = 0; w < 16; ++w) s += sl[w];
        out[b] = s;
    }
}

extern "C" void kernel_launch(void* const* d_in, const int* in_sizes, int n_in,
                              void* d_out, int out_size, void* d_ws, size_t ws_size,
                              hipStream_t stream) {
    const float* xs       = (const float*)d_in[0];
    const int*   A        = (const int*)  d_in[1];
    const float* cell_emb = (const float*)d_in[2];
    const float* Wg       = (const float*)d_in[3];
    const float* bg       = (const float*)d_in[4];
    const float* attnv    = (const float*)d_in[5];
    const float* Wt       = (const float*)d_in[6];
    const float* bt       = (const float*)d_in[7];
    const float* Wf       = (const float*)d_in[8];
    const float* bf       = (const float*)d_in[9];
    const float* Wf2      = (const float*)d_in[10];
    const float* bf2      = (const float*)d_in[11];
    const float* W1       = (const float*)d_in[12];
    const float* b1       = (const float*)d_in[13];
    const float* W2       = (const float*)d_in[14];
    const float* b2       = (const float*)d_in[15];
    const float* W3       = (const float*)d_in[16];
    const float* b3       = (const float*)d_in[17];
    const float* W4       = (const float*)d_in[18];
    const float* b4       = (const float*)d_in[19];
    float* out = (float*)d_out;

    float* W  = (float*)d_ws;
    float* X0 = W;                 // 64*4352
    float* X1 = W + 278528;        // 64*4352
    float* DM = W + 557056;        // 64*4*128

    k_gat<false><<<256, 1024, 0, stream>>>(xs, A, Wg, bg, attnv, X0,
                                           xs, Wt, bt, Wf, bf, Wf2, bf2, DM);
    k_gat<false><<<256, 1024, 0, stream>>>(X0, A, Wg + ATOM*ATOM, bg + ATOM, attnv + 2*ATOM, X1,
                                           xs, Wt, bt, Wf, bf, Wf2, bf2, DM);
    k_gat<true> <<<256, 1024, 0, stream>>>(X1, A, Wg + 2*ATOM*ATOM, bg + 2*ATOM, attnv + 4*ATOM, nullptr,
                                           xs, Wt, bt, Wf, bf, Wf2, bf2, DM);
    k_dec<<<64, 1024, 0, stream>>>(DM, cell_emb, W1, b1, W2, b2, W3, b3, W4, b4, out);
}

// Round 6
// 177.801 us; speedup vs baseline: 1.5620x; 1.5620x over previous
//
#include <hip/hip_runtime.h>

constexpr int ATOM = 34;
constexpr int HID = 256;
constexpr int LATENT = 128;
constexpr int CELLS = 512;
constexpr int NN = 128;
constexpr int NA = NN * ATOM;   // 4352
#define NEGF (-9e15f)

// ---------------- K1: fused GAT round ----------------
// grid 512 = 64 batches x 8 slices of 16 rows, block 256 (4 waves).
// LDS ~51 KB -> 2 blocks/CU co-resident (8 waves/CU). VGPR cap 256 (no spill).
__global__ __launch_bounds__(256, 2) void k_gat(
    const float* __restrict__ xsrc, const int* __restrict__ A,
    const float* __restrict__ Wg, const float* __restrict__ bg,
    const float* __restrict__ av, float* __restrict__ X)
{
    const int b = blockIdx.x >> 3, s8 = blockIdx.x & 7;
    const int t = threadIdx.x, lane = t & 63, wave = t >> 6;
    const int p0 = s8 * 16;

    __shared__ __align__(16) float xl[NN * 36];      // 18.4 KB
    __shared__ __align__(16) float hlT[ATOM * 132];  // 17.9 KB h transposed
    __shared__ __align__(16) float att[16 * NN];     // 8 KB
    __shared__ __align__(16) float wgT[ATOM * 36];   // 4.9 KB
    __shared__ float fs[NN], fd[NN], bgs[ATOM], avs[2 * ATOM];

    // ---- stage ----
    for (int i = t; i < ATOM * ATOM; i += 256) {
        int d = i / ATOM, e = i - d * ATOM;
        wgT[e * 36 + d] = Wg[i];
    }
    if (t < 68)  wgT[(t >> 1) * 36 + 34 + (t & 1)] = 0.f;   // zero pads
    if (t < ATOM)     bgs[t] = bg[t];
    if (t < 2 * ATOM) avs[t] = av[t];
    const float* xp = xsrc + b * NA;
    for (int i = t; i < NA; i += 256) xl[(i / ATOM) * 36 + (i % ATOM)] = xp[i];
    xl[(t >> 1) * 36 + 34 + (t & 1)] = 0.f;                 // all 256 pad slots
    __syncthreads();

    // ---- h^T = relu(x @ Wg + bg)^T : thread (n = t>>1, sub = t&1), 17 e's each ----
    {
        const int n = t >> 1, sub = t & 1;
        float xr[36];
        {
            float4* xr4 = (float4*)xr;
            const float4* p4 = (const float4*)(xl + n * 36);
            #pragma unroll
            for (int k = 0; k < 9; ++k) xr4[k] = p4[k];
        }
        #pragma unroll
        for (int j = 0; j < 17; ++j) {
            const int e = sub + 2 * j;
            float acc = bgs[e];
            const float4* wp = (const float4*)(wgT + e * 36);   // broadcast across lanes
            #pragma unroll
            for (int k = 0; k < 9; ++k) {
                float4 w = wp[k];
                acc += xr[4*k] * w.x + xr[4*k+1] * w.y + xr[4*k+2] * w.z + xr[4*k+3] * w.w;
            }
            hlT[e * 132 + n] = fmaxf(acc, 0.f);
        }
    }
    __syncthreads();

    // ---- fs/fd : all 256 threads (2 x 128) ----
    {
        const int n = t & 127, w = t >> 7;
        const float* avp = avs + w * ATOM;
        float acc = 0.f;
        #pragma unroll
        for (int d = 0; d < ATOM; ++d) acc += hlT[d * 132 + n] * avp[d];
        if (w == 0) fs[n] = acc; else fd[n] = acc;
    }
    __syncthreads();

    // ---- masked softmax: 4 waves x 4 rows ----
    const int* Ab = A + b * NN * NN;
    #pragma unroll
    for (int i = 0; i < 4; ++i) {
        int lp = wave * 4 + i, gp = p0 + lp;
        float fsv = fs[gp];
        unsigned long long m0 = __ballot(Ab[gp * NN + lane] > 0);
        unsigned long long m1 = __ballot(Ab[gp * NN + 64 + lane] > 0);
        float s0 = fsv + fd[lane];
        s0 = (s0 > 0.f) ? s0 : 0.01f * s0;
        if (!((m0 >> lane) & 1ull)) s0 = NEGF;
        float s1 = fsv + fd[64 + lane];
        s1 = (s1 > 0.f) ? s1 : 0.01f * s1;
        if (!((m1 >> lane) & 1ull)) s1 = NEGF;
        float mx = fmaxf(s0, s1);
        #pragma unroll
        for (int o = 32; o >= 1; o >>= 1) mx = fmaxf(mx, __shfl_xor(mx, o, 64));
        float e0 = __expf(s0 - mx), e1 = __expf(s1 - mx);
        float sm = e0 + e1;
        #pragma unroll
        for (int o = 32; o >= 1; o >>= 1) sm += __shfl_xor(sm, o, 64);
        float inv = 1.f / sm;
        att[lp * NN + lane]      = e0 * inv;
        att[lp * NN + 64 + lane] = e1 * inv;
    }
    __syncthreads();

    // ---- x_out = x + att @ h : thread (p = t>>4, g = t&15) owns d={g,g+16,(g+32 if g<2)} ----
    {
        const int p = t >> 4, g = t & 15, gp = p0 + p;
        const float4* ap  = (const float4*)(att + p * NN);
        const float4* h1p = (const float4*)(hlT + g * 132);
        const float4* h2p = (const float4*)(hlT + (g + 16) * 132);
        float a1 = 0.f, a2 = 0.f;
        #pragma unroll 8
        for (int k = 0; k < 32; ++k) {
            float4 a4 = ap[k], x1 = h1p[k], x2 = h2p[k];
            a1 += a4.x * x1.x + a4.y * x1.y + a4.z * x1.z + a4.w * x1.w;
            a2 += a4.x * x2.x + a4.y * x2.y + a4.z * x2.z + a4.w * x2.w;
        }
        float* Xr = X + b * NA + gp * ATOM;
        Xr[g]      = xl[gp * 36 + g] + a1;
        Xr[g + 16] = xl[gp * 36 + g + 16] + a2;
        if (g < 2) {
            const float4* h3p = (const float4*)(hlT + (g + 32) * 132);
            float a3 = 0.f;
            #pragma unroll 8
            for (int k = 0; k < 32; ++k) {
                float4 a4 = ap[k], x3 = h3p[k];
                a3 += a4.x * x3.x + a4.y * x3.y + a4.z * x3.z + a4.w * x3.w;
            }
            Xr[g + 32] = xl[gp * 36 + g + 32] + a3;
        }
    }
}

// ---------------- K2: phaseB (round-4 proven version) ----------------
// grid 256, block 512 = 32 rows x 16 h-subgroups; float4 LDS reads throughout.
__global__ __launch_bounds__(512, 2) void k_phaseB(
    const float* __restrict__ X, const float* __restrict__ xs,
    const float* __restrict__ Wt, const float* __restrict__ bt,
    const float* __restrict__ Wf, const float* __restrict__ bf,
    const float* __restrict__ Wf2, const float* __restrict__ bf2,
    float* __restrict__ DM)
{
    const int b = blockIdx.x >> 2, q4 = blockIdx.x & 3;
    const int t = threadIdx.x;
    const int p0 = q4 * 32;
    __shared__ float wt[HID * 36];       // [h][d] transposed; reused: partials 0..7
    __shared__ float wf[HID * 36];       // [h][j];            reused: partials 8..15
    __shared__ float xl[32][36];
    __shared__ float dlT[ATOM][33];
    __shared__ float wf2s[ATOM * LATENT];
    __shared__ float bts[HID];
    __shared__ float bfs[ATOM];
    __shared__ float sl[512];

    for (int i = t; i < ATOM * HID; i += 512) {
        int d = i >> 8, h = i & 255;               // Wt is [d][h]
        wt[h * 36 + d] = Wt[i];
    }
    for (int i = t; i < HID * ATOM; i += 512) {
        int h = i / ATOM, j = i % ATOM;            // Wf is [h][j]
        wf[h * 36 + j] = Wf[i];
    }
    for (int i = t; i < ATOM * LATENT; i += 512) wf2s[i] = Wf2[i];
    if (t < HID)  bts[t] = bt[t];
    if (t < ATOM) bfs[t] = bf[t];
    for (int i = t; i < 32 * ATOM; i += 512) xl[i / ATOM][i % ATOM] = X[b * NA + p0 * ATOM + i];
    __syncthreads();

    const int row = t & 31, sub = t >> 5;          // sub 0..15
    float dp[ATOM];
    #pragma unroll
    for (int j = 0; j < ATOM; ++j) dp[j] = 0.f;
    {
        float xr[36];
        float4* xr4 = (float4*)xr;
        const float4* xlr = (const float4*)&xl[row][0];
        #pragma unroll
        for (int k = 0; k < 9; ++k) xr4[k] = xlr[k];
        for (int i = 0; i < 16; ++i) {
            const int h = sub + 16 * i;
            float acc = bts[h];
            const float4* wtp = (const float4*)&wt[h * 36];
            #pragma unroll
            for (int k = 0; k < 8; ++k) {
                float4 w4 = wtp[k];
                acc += xr[4*k] * w4.x + xr[4*k+1] * w4.y + xr[4*k+2] * w4.z + xr[4*k+3] * w4.w;
            }
            acc += xr[32] * wt[h * 36 + 32] + xr[33] * wt[h * 36 + 33];
            acc = fmaxf(acc, 0.f);
            const float4* wfp = (const float4*)&wf[h * 36];
            #pragma unroll
            for (int k = 0; k < 8; ++k) {
                float4 w4 = wfp[k];
                dp[4*k]   += acc * w4.x; dp[4*k+1] += acc * w4.y;
                dp[4*k+2] += acc * w4.z; dp[4*k+3] += acc * w4.w;
            }
            dp[32] += acc * wf[h * 36 + 32];
            dp[33] += acc * wf[h * 36 + 33];
        }
    }
    __syncthreads();                               // done with wt/wf weights
    {
        float* pl = (sub < 8) ? wt : wf;
        const int s8 = sub & 7;
        #pragma unroll
        for (int j = 0; j < ATOM; ++j) pl[(s8 * 32 + row) * ATOM + j] = dp[j];
    }
    __syncthreads();
    for (int i = t; i < 32 * ATOM; i += 512) {
        int rr = i / ATOM, j = i % ATOM;
        float dv = bfs[j] + xs[b * NA + (p0 + rr) * ATOM + j];
        #pragma unroll
        for (int s = 0; s < 8; ++s)
            dv += wt[(s * 32 + rr) * ATOM + j] + wf[(s * 32 + rr) * ATOM + j];
        dlT[j][rr] = dv;
    }
    __syncthreads();
    {
        const int l = t & 127, chunk = t >> 7;
        float w2r[ATOM];
        #pragma unroll
        for (int j = 0; j < ATOM; ++j) w2r[j] = wf2s[j * LATENT + l];
        float mx = -3.4e38f;
        for (int rr = chunk * 8; rr < chunk * 8 + 8; ++rr) {
            float acc = bf2[l];
            #pragma unroll
            for (int j = 0; j < ATOM; ++j) acc += dlT[j][rr] * w2r[j];
            mx = fmaxf(mx, acc);
        }
        sl[chunk * 128 + l] = mx;
    }
    __syncthreads();
    if (t < LATENT)
        DM[(b * 4 + q4) * LATENT + t] =
            fmaxf(fmaxf(sl[t], sl[128 + t]), fmaxf(sl[256 + t], sl[384 + t]));
}

// ---------------- K3: full decoder, k-split partial sums ----------------
// grid 64, block 1024 (16 waves). VGPR use is tiny (~28), no spill risk.
__global__ __launch_bounds__(1024) void k_dec(
    const float* __restrict__ DM, const float* __restrict__ cell,
    const float* __restrict__ W1, const float* __restrict__ b1,
    const float* __restrict__ W2, const float* __restrict__ b2,
    const float* __restrict__ W3, const float* __restrict__ b3,
    const float* __restrict__ W4, const float* __restrict__ b4,
    float* __restrict__ out)
{
    const int b = blockIdx.x, t = threadIdx.x, lane = t & 63, wave = t >> 6;
    __shared__ float vec[LATENT + CELLS];
    __shared__ float h1[128], h2[256], h3[512];
    __shared__ float sl[1024];
    if (t < LATENT) {
        float m = fmaxf(fmaxf(DM[(b*4+0)*LATENT + t], DM[(b*4+1)*LATENT + t]),
                        fmaxf(DM[(b*4+2)*LATENT + t], DM[(b*4+3)*LATENT + t]));
        vec[t] = 1.f / (1.f + __expf(-m));
    } else if (t >= 512) {
        int c = t - 512;
        vec[LATENT + c] = 1.f / (1.f + __expf(-cell[b * CELLS + c]));
    }
    __syncthreads();
    {
        const int j = t & 127, part = t >> 7;
        float acc = 0.f;
        #pragma unroll 4
        for (int k = part * 80; k < part * 80 + 80; ++k)
            acc += vec[k] * W1[k * 128 + j];
        sl[part * 128 + j] = acc;
    }
    __syncthreads();
    if (t < 128) {
        float v = b1[t];
        #pragma unroll
        for (int p = 0; p < 8; ++p) v += sl[p * 128 + t];
        h1[t] = fmaxf(v, 0.f);
    }
    __syncthreads();
    {
        const int j = t & 255, part = t >> 8;
        float acc = 0.f;
        #pragma unroll 4
        for (int k = part * 32; k < part * 32 + 32; ++k)
            acc += h1[k] * W2[k * 256 + j];
        sl[part * 256 + j] = acc;
    }
    __syncthreads();
    if (t < 256) h2[t] = fmaxf(sl[t] + sl[256 + t] + sl[512 + t] + sl[768 + t] + b2[t], 0.f);
    __syncthreads();
    {
        const int j = t & 511, part = t >> 9;
        float acc = 0.f;
        #pragma unroll 4
        for (int k = part * 128; k < part * 128 + 128; ++k)
            acc += h2[k] * W3[k * 512 + j];
        sl[part * 512 + j] = acc;
    }
    __syncthreads();
    if (t < 512) h3[t] = fmaxf(sl[t] + sl[512 + t] + b3[t], 0.f);
    __syncthreads();
    float v = (t < 512) ? h3[t] * W4[t] : 0.f;
    #pragma unroll
    for (int o = 32; o >= 1; o >>= 1) v += __shfl_xor(v, o, 64);
    if (lane == 0) sl[wave] = v;
    __syncthreads();
    if (t == 0) {
        float s = b4[0];
        #pragma unroll
        for (int w = 0; w < 16; ++w) s += sl[w];
        out[b] = s;
    }
}

extern "C" void kernel_launch(void* const* d_in, const int* in_sizes, int n_in,
                              void* d_out, int out_size, void* d_ws, size_t ws_size,
                              hipStream_t stream) {
    const float* xs       = (const float*)d_in[0];
    const int*   A        = (const int*)  d_in[1];
    const float* cell_emb = (const float*)d_in[2];
    const float* Wg       = (const float*)d_in[3];
    const float* bg       = (const float*)d_in[4];
    const float* attnv    = (const float*)d_in[5];
    const float* Wt       = (const float*)d_in[6];
    const float* bt       = (const float*)d_in[7];
    const float* Wf       = (const float*)d_in[8];
    const float* bf       = (const float*)d_in[9];
    const float* Wf2      = (const float*)d_in[10];
    const float* bf2      = (const float*)d_in[11];
    const float* W1       = (const float*)d_in[12];
    const float* b1       = (const float*)d_in[13];
    const float* W2       = (const float*)d_in[14];
    const float* b2       = (const float*)d_in[15];
    const float* W3       = (const float*)d_in[16];
    const float* b3       = (const float*)d_in[17];
    const float* W4       = (const float*)d_in[18];
    const float* b4       = (const float*)d_in[19];
    float* out = (float*)d_out;

    float* W  = (float*)d_ws;
    float* X0 = W;                 // 64*4352
    float* X1 = W + 278528;        // 64*4352  (ping-pong: no cross-block in-place race)
    float* DM = W + 557056;        // 64*4*128

    k_gat<<<512, 256, 0, stream>>>(xs, A, Wg,                   bg,            attnv,           X0);
    k_gat<<<512, 256, 0, stream>>>(X0, A, Wg + ATOM * ATOM,     bg + ATOM,     attnv + 2*ATOM,  X1);
    k_gat<<<512, 256, 0, stream>>>(X1, A, Wg + 2 * ATOM * ATOM, bg + 2 * ATOM, attnv + 4*ATOM,  X0);
    k_phaseB<<<256, 512, 0, stream>>>(X0, xs, Wt, bt, Wf, bf, Wf2, bf2, DM);
    k_dec<<<64, 1024, 0, stream>>>(DM, cell_emb, W1, b1, W2, b2, W3, b3, W4, b4, out);
}